// Round 3
// baseline (456.838 us; speedup 1.0000x reference)
//
#include <hip/hip_runtime.h>
#include <stdint.h>

// Problem constants (fixed by reference: L=1024, B=8, D=2048)
#define L_SEQ 1024
#define BATCH 8
#define DIM   2048
#define GM    8192   // L*B
#define GN    6144   // 3*D
#define GK    2048   // D
#define SCALE_X 1.7320508075688772f  // sqrt(1 + 2*exp(0))
#define SCAN_PF 16
#define W_ILV  8192  // U' row width (elements) when x is interleaved

// GEMM geometry: 256x256 tile, k-ring of 4 slices of 32
#define BM 256
#define BN 256
#define BKC 32
#define NCHUNK 64    // GK / BKC

using bf16x8  = __attribute__((ext_vector_type(8))) __bf16;
using floatx4 = __attribute__((ext_vector_type(4))) float;

__device__ __forceinline__ unsigned short f2bf(float f) {
  unsigned u = __float_as_uint(f);
  u += 0x7FFFu + ((u >> 16) & 1u);   // round-to-nearest-even
  return (unsigned short)(u >> 16);
}
__device__ __forceinline__ float sigmoidf_fast(float z) {
  return __builtin_amdgcn_rcpf(1.0f + __expf(-z));
}
__device__ __forceinline__ void async16(const unsigned short* g, unsigned short* l) {
  __builtin_amdgcn_global_load_lds(
      (__attribute__((address_space(1))) unsigned int*)g,
      (__attribute__((address_space(3))) unsigned int*)l,
      16, 0, 0);
}

// ---------------- cast x (fp32) -> A (bf16); ILV also scatters x into U' -------
template <bool ILV>
__global__ __launch_bounds__(256) void cast_x_kernel(const float4* __restrict__ xin,
                                                     unsigned short* __restrict__ Aout,
                                                     unsigned short* __restrict__ Ux) {
  const int n4 = (GM * GK) / 4;
  for (int i = blockIdx.x * blockDim.x + threadIdx.x; i < n4; i += gridDim.x * blockDim.x) {
    float4 v = xin[i];
    union { unsigned short s[4]; unsigned long long ll; } o;
    o.s[0] = f2bf(v.x); o.s[1] = f2bf(v.y); o.s[2] = f2bf(v.z); o.s[3] = f2bf(v.w);
    *(unsigned long long*)&Aout[(size_t)i * 4] = o.ll;
    if (ILV) {
      const int f = i * 4;                    // flat (gm,d); d..d+3 in one row
      const int gm = f >> 11, d = f & (DIM - 1);
      unsigned short* dst = Ux + (size_t)gm * W_ILV + 2 * d + 1;  // odd slots
      dst[0] = o.s[0]; dst[2] = o.s[1]; dst[4] = o.s[2]; dst[6] = o.s[3];
    }
  }
}

// ------------- transpose-cast W (GK x GN fp32) -> Bt (GN' x GK bf16) ------------
// Column permutation: W col n = 3d+j -> j==0: Bt row d (u0 plane)
//                                       j>0 : Bt row DIM + 2d + (j-1) (u1u2 pairs)
__global__ __launch_bounds__(256) void transpose_w_kernel(const float* __restrict__ W,
                                                          unsigned short* __restrict__ Bt) {
  __shared__ float tile[32][33];
  const int tx = threadIdx.x & 31, ty = threadIdx.x >> 5;
  const int n0 = blockIdx.x * 32;
  const int k0 = blockIdx.y * 32;
#pragma unroll
  for (int r = 0; r < 32; r += 8)
    tile[ty + r][tx] = W[(size_t)(k0 + ty + r) * GN + n0 + tx];
  __syncthreads();
#pragma unroll
  for (int r = 0; r < 32; r += 8) {
    const int n = n0 + ty + r;
    const int dq = n / 3, j = n - 3 * dq;
    const int np = (j == 0) ? dq : (DIM + 2 * dq + (j - 1));
    Bt[(size_t)np * GK + k0 + tx] = f2bf(tile[tx][ty + r]);
  }
}

// ---------------- GEMM: U = A(GM x GK) * Bt(GN x GK)^T, bf16 out ----------------
// 256x256 tile, 8 waves (2M x 4N), per-wave 128x64 = 8x4 reps of 16x16x32 MFMA.
// LDS = ring of 4 k-slices (k=32 each) per matrix: 4*16KB*2 = 128 KB.
// Pipeline: per chunk c: s_waitcnt vmcnt(8) (drains chunk c only; c+1,c+2 stay
// in flight) -> raw s_barrier -> interleaved {ds_read next cluster || 8 MFMA}
// x4 clusters with rotating operand regs; stage chunk c+3 under clusters 1-2.
// vmcnt never drains to 0 in the main loop (T3+T4); tail peels 61/62/63.
//
// Intra-chunk interleave (this round's change): the compiler front-loads all 12
// ds_reads before the MFMA block, serializing LDS BW with the MFMA pipe under
// barrier lockstep (measured: chunk 2607 cyc ~ MFMA 1242 + LDS 1100 + ovh).
// Forced schedule: 4 clusters of 8 MFMA; cluster k+1's A-frag reads issue
// BEFORE cluster k's MFMAs (in-order issue slots them into MFMA pipe stalls),
// so every lgkmcnt(0) except the chunk-entry one is pre-satisfied. Rotating
// aL0/aH0 <-> aL1/aH1 avoids WAR on MFMA operands; asm lgkmcnt + sched_barrier
// fences (rule #18) pin the order. Per-acc MFMA order unchanged -> numerics
// bit-identical.
//
// LDS swizzle: 16B slot S(row,s) = (row>>1)*8 + (((row&1)*4+s)^((row>>1)&7));
// applied on ds_read addr, inverted on per-thread GLOBAL source (LDS dest of
// global_load_lds stays lane-linear). Worst case 2-way on ds_read_b128 (free).
//
// XCD-rectangle swizzle (T1): flat id f -> xcd=f&7, rnd=(f>>3)>>5, s=(f>>3)&31
// -> y=4*xcd+(s&3), x=8*rnd+(s>>2). Bijective over 768 = 8x3x32; keeps each
// XCD's concurrent A working set (4 MB) inside its 4 MB L2 (FETCH 176->148 MB).

#define WAITV(N) asm volatile("s_waitcnt vmcnt(" #N ")" ::: "memory")
#define LGKM0 asm volatile("s_waitcnt lgkmcnt(0)" ::: "memory"); \
              __builtin_amdgcn_sched_barrier(0)

#define MM2(I, AL, AH)                                                        \
    __builtin_amdgcn_s_setprio(1);                                            \
    _Pragma("unroll") for (int nt = 0; nt < 4; ++nt)                          \
        acc[(I)][nt] = __builtin_amdgcn_mfma_f32_16x16x32_bf16(               \
            (AL), bF[nt], acc[(I)][nt], 0, 0, 0);                             \
    _Pragma("unroll") for (int nt = 0; nt < 4; ++nt)                          \
        acc[(I) + 1][nt] = __builtin_amdgcn_mfma_f32_16x16x32_bf16(           \
            (AH), bF[nt], acc[(I) + 1][nt], 0, 0, 0);                         \
    __builtin_amdgcn_s_setprio(0);                                            \
    __builtin_amdgcn_sched_barrier(0);

#define CHUNK(cexpr, SL, DOSTAGE)                                             \
  {                                                                           \
    __builtin_amdgcn_s_barrier();                                             \
    __builtin_amdgcn_sched_barrier(0);                                        \
    const int c_ = (cexpr);                                                   \
    const char* aB_ = AsB + (SL) * 16384;                                     \
    const char* bB_ = BsB + (SL) * 16384;                                     \
    bf16x8 bF[4], aL0, aH0, aL1, aH1;                                         \
    _Pragma("unroll") for (int nt = 0; nt < 4; ++nt)                          \
        bF[nt] = *(const bf16x8*)(bB_ + SB0 + nt * 1024);                     \
    aL0 = *(const bf16x8*)(aB_ + SA0);                                        \
    aH0 = *(const bf16x8*)(aB_ + SA0 + 1024);                                 \
    LGKM0;                                                                    \
    aL1 = *(const bf16x8*)(aB_ + SA0 + 2048);                                 \
    aH1 = *(const bf16x8*)(aB_ + SA0 + 3072);                                 \
    if (DOSTAGE) {                                                            \
      unsigned short* ad_ = (unsigned short*)(AsL + ((c_ + 3) & 3) * 16384);  \
      const int ko_ = (c_ + 3) * BKC;                                         \
      async16(aG0 + ko_, ad_ + L0 * 8);                                       \
      async16(aG1 + ko_, ad_ + L1 * 8);                                       \
    }                                                                         \
    MM2(0, aL0, aH0);                                                         \
    LGKM0;                                                                    \
    aL0 = *(const bf16x8*)(aB_ + SA0 + 4096);                                 \
    aH0 = *(const bf16x8*)(aB_ + SA0 + 5120);                                 \
    if (DOSTAGE) {                                                            \
      unsigned short* bd_ = (unsigned short*)(BsL + ((c_ + 3) & 3) * 16384);  \
      const int ko_ = (c_ + 3) * BKC;                                         \
      async16(bG0 + ko_, bd_ + L0 * 8);                                       \
      async16(bG1 + ko_, bd_ + L1 * 8);                                       \
    }                                                                         \
    MM2(2, aL1, aH1);                                                         \
    LGKM0;                                                                    \
    aL1 = *(const bf16x8*)(aB_ + SA0 + 6144);                                 \
    aH1 = *(const bf16x8*)(aB_ + SA0 + 7168);                                 \
    MM2(4, aL0, aH0);                                                         \
    LGKM0;                                                                    \
    MM2(6, aL1, aH1);                                                         \
  }

template <bool ILV>
__global__ __launch_bounds__(512, 2) void gemm_kernel(const unsigned short* __restrict__ A,
                                                      const unsigned short* __restrict__ Bt,
                                                      unsigned short* __restrict__ U) {
  __shared__ alignas(16) unsigned short As[4][BM * BKC];  // 64 KB
  __shared__ alignas(16) unsigned short Bs[4][BN * BKC];  // 64 KB
  const int tid  = threadIdx.x;
  const int wave = tid >> 6, lane = tid & 63;
  const int quad = lane >> 4, lrow = lane & 15;
  const int wm = (wave >> 2) * 128;   // 2 M-waves
  const int wn = (wave & 3) * 64;    // 4 N-waves

  // XCD-rectangle swizzle: 768 blocks = 8 XCD x 3 rounds x (4y x 8x) rectangles
  const int f    = blockIdx.y * (GN / BN) + blockIdx.x;  // flat dispatch id
  const int xcd  = f & 7;
  const int slot = f >> 3;
  const int rnd  = slot >> 5;        // 0..2
  const int ss   = slot & 31;        // 0..31
  const int mBase = (4 * xcd + (ss & 3)) * BM;   // y-tile 0..31
  const int nBase = (8 * rnd + (ss >> 2)) * BN;  // x-tile 0..23

  floatx4 acc[8][4] = {};

  // staging: thread owns 16B slots L0=tid, L1=tid+512 of each slice (lane-linear
  // LDS dest). Invert swizzle to find the (row, k-slot) this slot must hold.
  const int L0 = tid, L1 = tid + 512;
  int r0, s0, r1, s1;
  { const int p = L0 >> 3, w = L0 & 7, v = w ^ (p & 7); r0 = 2 * p + (v >> 2); s0 = v & 3; }
  { const int p = L1 >> 3, w = L1 & 7, v = w ^ (p & 7); r1 = 2 * p + (v >> 2); s1 = v & 3; }
  const unsigned short* aG0 = A  + (size_t)(mBase + r0) * GK + s0 * 8;
  const unsigned short* aG1 = A  + (size_t)(mBase + r1) * GK + s1 * 8;
  const unsigned short* bG0 = Bt + (size_t)(nBase + r0) * GK + s0 * 8;
  const unsigned short* bG1 = Bt + (size_t)(nBase + r1) * GK + s1 * 8;

  // ds_read byte offsets within a slice (mt adds 16 rows = +1024 B)
  const int rA = wm + lrow;
  const int SA0 = (rA >> 1) * 128 + ((((rA & 1) * 4 + quad) ^ ((rA >> 1) & 7)) * 16);
  const int rB = wn + lrow;
  const int SB0 = (rB >> 1) * 128 + ((((rB & 1) * 4 + quad) ^ ((rB >> 1) & 7)) * 16);
  const char* AsB = (const char*)As;
  const char* BsB = (const char*)Bs;
  char* AsL = (char*)As;
  char* BsL = (char*)Bs;

  // prologue: stage chunks 0,1,2 (12 loads/thread in flight)
#pragma unroll
  for (int c = 0; c < 3; ++c) {
    unsigned short* ad = (unsigned short*)(AsL + c * 16384);
    unsigned short* bd = (unsigned short*)(BsL + c * 16384);
    async16(aG0 + c * BKC, ad + L0 * 8);
    async16(aG1 + c * BKC, ad + L1 * 8);
    async16(bG0 + c * BKC, bd + L0 * 8);
    async16(bG1 + c * BKC, bd + L1 * 8);
  }

  // main loop: chunks 0..59 (stage c+3), then peeled 60..63
#pragma unroll 1
  for (int cc = 0; cc < 15; ++cc) {
    const int cb = cc * 4;
#pragma unroll
    for (int j = 0; j < 4; ++j) {
      WAITV(8);
      CHUNK(cb + j, j, true);
    }
  }
  WAITV(8); CHUNK(60, 0, true);   // stages chunk 63
  WAITV(8); CHUNK(61, 1, false);
  WAITV(4); CHUNK(62, 2, false);
  WAITV(0); CHUNK(63, 3, false);

  // C/D layout: col = lane&15 (N), row = quad*4 + reg (M)
  const int rowW = ILV ? W_ILV : GN;
#pragma unroll
  for (int mt = 0; mt < 8; ++mt) {
    const int gm = mBase + wm + mt * 16 + quad * 4;
#pragma unroll
    for (int nt = 0; nt < 4; ++nt) {
      const int gn = nBase + wn + nt * 16 + lrow;
      const int col = ILV ? ((gn < DIM) ? 2 * gn : gn + DIM) : gn;  // u0 even slots / u1u2 block
#pragma unroll
      for (int q = 0; q < 4; ++q)
        U[(size_t)(gm + q) * rowW + col] = f2bf(acc[mt][nt][q]);
    }
  }
}

// ---------------- SRU scan (ILV): 2 dword loads + 1 store per step --------------
// U' row gm: [ (u0,x) pairs, 2D elems ][ (u1,u2) pairs, 2D elems ].
// Rotating raw-register prefetch depth 16 -> 48 outstanding vm-ops (<=63 cap).
__global__ __launch_bounds__(64) void sru_scan_ilv(const unsigned short* __restrict__ U,
                                                   const float* __restrict__ c0,
                                                   const float* __restrict__ wc,
                                                   const float* __restrict__ bias,
                                                   float* __restrict__ out) {
  const int e = blockIdx.x * 64 + threadIdx.x;
  const int b = e >> 11, d = e & (DIM - 1);
  const float vf = wc[d], vr = wc[DIM + d];
  const float bfv = bias[d], brv = bias[DIM + d];
  float c = c0[e];

  constexpr int PF = SCAN_PF;
  constexpr int UD = BATCH * W_ILV / 2;  // dwords per l-step in U'
  constexpr int XS = BATCH * DIM;

  const unsigned* u0x = (const unsigned*)(U + (size_t)b * W_ILV + 2 * d);
  const unsigned* u12 = (const unsigned*)(U + (size_t)b * W_ILV + 2 * DIM + 2 * d);
  float* hp = out + (size_t)b * DIM + d;

  unsigned p0x[PF], p12[PF];
#pragma unroll
  for (int j = 0; j < PF; ++j) {
    p0x[j] = u0x[(size_t)j * UD];
    p12[j] = u12[(size_t)j * UD];
  }
  const unsigned* f0x = u0x + (size_t)PF * UD;
  const unsigned* f12 = u12 + (size_t)PF * UD;

  for (int l0 = 0; l0 < L_SEQ; l0 += PF) {
#pragma unroll
    for (int j = 0; j < PF; ++j) {
      const unsigned ra = p0x[j], rb = p12[j];
      p0x[j] = *f0x; p12[j] = *f12;        // raw prefetch, consumed PF iters later
      f0x += UD; f12 += UD;
      const float a0 = __uint_as_float(ra << 16);
      const float ax = __uint_as_float(ra & 0xFFFF0000u) * SCALE_X;
      const float u1 = __uint_as_float(rb << 16);
      const float u2 = __uint_as_float(rb & 0xFFFF0000u);
      const float f = sigmoidf_fast(u1 + fmaf(vf, c, bfv));
      c = fmaf(c - a0, f, a0);
      const float rr = sigmoidf_fast(u2 + fmaf(vr, c, brv));
      *hp = fmaf(rr, c - ax, ax);
      hp += XS;
    }
  }
  out[(size_t)L_SEQ * XS + e] = c;
}

// ---------------- SRU scan (fallback, r3 layout: separate x in A_bf) ------------
__global__ __launch_bounds__(64) void sru_scan_flat(const unsigned short* __restrict__ U,
                                                    const unsigned short* __restrict__ xbf,
                                                    const float* __restrict__ c0,
                                                    const float* __restrict__ wc,
                                                    const float* __restrict__ bias,
                                                    float* __restrict__ out) {
  const int e = blockIdx.x * 64 + threadIdx.x;
  const int b = e >> 11, d = e & (DIM - 1);
  const float vf = wc[d], vr = wc[DIM + d];
  const float bfv = bias[d], brv = bias[DIM + d];
  float c = c0[e];

  constexpr int PF = SCAN_PF;
  constexpr int US = BATCH * GN;
  constexpr int XS = BATCH * DIM;

  const unsigned short* u0p  = U + (size_t)b * GN + d;
  const unsigned short* u12p = U + (size_t)b * GN + DIM + 2 * d;
  const unsigned short* xp   = xbf + (size_t)b * DIM + d;
  float* hp = out + (size_t)b * DIM + d;

  unsigned pu0[PF], pu12[PF], pux[PF];
#pragma unroll
  for (int j = 0; j < PF; ++j) {
    pu0[j]  = u0p[(size_t)j * US];
    pu12[j] = *(const unsigned*)(u12p + (size_t)j * US);
    pux[j]  = xp[(size_t)j * XS];
  }
  const unsigned short* uf0  = u0p + (size_t)PF * US;
  const unsigned short* uf12 = u12p + (size_t)PF * US;
  const unsigned short* xf   = xp + (size_t)PF * XS;

  for (int l0 = 0; l0 < L_SEQ; l0 += PF) {
#pragma unroll
    for (int j = 0; j < PF; ++j) {
      const unsigned r0 = pu0[j], r12 = pu12[j], rx = pux[j];
      pu0[j]  = uf0[0];
      pu12[j] = *(const unsigned*)uf12;
      pux[j]  = xf[0];
      uf0 += US; uf12 += US; xf += XS;
      const float a0 = __uint_as_float(r0 << 16);
      const float u1 = __uint_as_float(r12 << 16);
      const float u2 = __uint_as_float(r12 & 0xFFFF0000u);
      const float ax = __uint_as_float(rx << 16) * SCALE_X;
      const float f = sigmoidf_fast(u1 + fmaf(vf, c, bfv));
      c = fmaf(c - a0, f, a0);
      const float rr = sigmoidf_fast(u2 + fmaf(vr, c, brv));
      *hp = fmaf(rr, c - ax, ax);
      hp += XS;
    }
  }
  out[(size_t)L_SEQ * XS + e] = c;
}

// --------------------------------- launcher ------------------------------------
extern "C" void kernel_launch(void* const* d_in, const int* in_sizes, int n_in,
                              void* d_out, int out_size, void* d_ws, size_t ws_size,
                              hipStream_t stream) {
  const float* x    = (const float*)d_in[0];
  const float* c0   = (const float*)d_in[1];
  const float* W    = (const float*)d_in[2];
  const float* wc   = (const float*)d_in[3];
  const float* bias = (const float*)d_in[4];
  float* out = (float*)d_out;

  char* ws = (char*)d_ws;
  // ILV layout: A 33,554,432 | Bt 25,165,824 | U' 134,217,728 + pad 2,097,152
  const size_t ILV_NEED = 33554432u + 25165824u + 134217728u + 2097152u;  // 195,035,136

  if (ws_size >= ILV_NEED) {
    unsigned short* A_bf  = (unsigned short*)(ws);
    unsigned short* Bt_bf = (unsigned short*)(ws + 33554432);
    unsigned short* U_bf  = (unsigned short*)(ws + 58720256);
    cast_x_kernel<true><<<4096, 256, 0, stream>>>((const float4*)x, A_bf, U_bf);
    transpose_w_kernel<<<dim3(GN / 32, GK / 32), 256, 0, stream>>>(W, Bt_bf);
    gemm_kernel<true><<<dim3(GN / BN, GM / BM), 512, 0, stream>>>(A_bf, Bt_bf, U_bf);
    sru_scan_ilv<<<256, 64, 0, stream>>>(U_bf, c0, wc, bias, out);
  } else {
    // r3 layout: A (+scan pad) | Bt | U (GN width, + pad)
    unsigned short* A_bf  = (unsigned short*)(ws);
    unsigned short* Bt_bf = (unsigned short*)(ws + 34078720);
    unsigned short* U_bf  = (unsigned short*)(ws + 59244544);
    cast_x_kernel<false><<<4096, 256, 0, stream>>>((const float4*)x, A_bf, nullptr);
    transpose_w_kernel<<<dim3(GN / 32, GK / 32), 256, 0, stream>>>(W, Bt_bf);
    gemm_kernel<false><<<dim3(GN / BN, GM / BM), 512, 0, stream>>>(A_bf, Bt_bf, U_bf);
    sru_scan_flat<<<256, 64, 0, stream>>>(U_bf, A_bf, c0, wc, bias, out);
  }
}

// Round 4
// 451.534 us; speedup vs baseline: 1.0117x; 1.0117x over previous
//
#include <hip/hip_runtime.h>
#include <stdint.h>

// Problem constants (fixed by reference: L=1024, B=8, D=2048)
#define L_SEQ 1024
#define BATCH 8
#define DIM   2048
#define GM    8192   // L*B
#define GN    6144   // 3*D
#define GK    2048   // D
#define SCALE_X 1.7320508075688772f  // sqrt(1 + 2*exp(0))
#define SCAN_PF 16

// GEMM geometry: 256x128 tile, 4 waves (2M x 2N), ring of 3 k-slices of 32
#define BM 256
#define BN 128
#define BKC 32

using bf16x8  = __attribute__((ext_vector_type(8))) __bf16;
using floatx4 = __attribute__((ext_vector_type(4))) float;

__device__ __forceinline__ unsigned short f2bf(float f) {
  unsigned u = __float_as_uint(f);
  u += 0x7FFFu + ((u >> 16) & 1u);   // round-to-nearest-even
  return (unsigned short)(u >> 16);
}
__device__ __forceinline__ float sigmoidf_fast(float z) {
  return __builtin_amdgcn_rcpf(1.0f + __expf(-z));
}
__device__ __forceinline__ void async16(const unsigned short* g, unsigned short* l) {
  __builtin_amdgcn_global_load_lds(
      (__attribute__((address_space(1))) unsigned int*)g,
      (__attribute__((address_space(3))) unsigned int*)l,
      16, 0, 0);
}

// ---------------- cast x (fp32) -> A (bf16), pure streaming ---------------------
__global__ __launch_bounds__(256) void cast_x_kernel(const float4* __restrict__ xin,
                                                     unsigned short* __restrict__ Aout) {
  const int n4 = (GM * GK) / 4;
  for (int i = blockIdx.x * blockDim.x + threadIdx.x; i < n4; i += gridDim.x * blockDim.x) {
    float4 v = xin[i];
    union { unsigned short s[4]; unsigned long long ll; } o;
    o.s[0] = f2bf(v.x); o.s[1] = f2bf(v.y); o.s[2] = f2bf(v.z); o.s[3] = f2bf(v.w);
    *(unsigned long long*)&Aout[(size_t)i * 4] = o.ll;
  }
}

// ------------- transpose-cast W (GK x GN fp32) -> Bt (GN' x GK bf16) ------------
// Column permutation: W col n = 3d+j -> j==0: Bt row d (u0 plane)
//                                       j>0 : Bt row DIM + 2d + (j-1) (u1u2 pairs)
__global__ __launch_bounds__(256) void transpose_w_kernel(const float* __restrict__ W,
                                                          unsigned short* __restrict__ Bt) {
  __shared__ float tile[32][33];
  const int tx = threadIdx.x & 31, ty = threadIdx.x >> 5;
  const int n0 = blockIdx.x * 32;
  const int k0 = blockIdx.y * 32;
#pragma unroll
  for (int r = 0; r < 32; r += 8)
    tile[ty + r][tx] = W[(size_t)(k0 + ty + r) * GN + n0 + tx];
  __syncthreads();
#pragma unroll
  for (int r = 0; r < 32; r += 8) {
    const int n = n0 + ty + r;
    const int dq = n / 3, j = n - 3 * dq;
    const int np = (j == 0) ? dq : (DIM + 2 * dq + (j - 1));
    Bt[(size_t)np * GK + k0 + tx] = f2bf(tile[tx][ty + r]);
  }
}

// ---------------- GEMM: U = A(GM x GK) * Bt(GN x GK)^T, bf16 out ----------------
// 256x128 tile, 4 waves (2M x 2N), per-wave 128x64 = 8x4 reps of 16x16x32 MFMA
// (per-wave code identical to the previous 512-thread kernel -> bit-identical
// accumulation). LDS = ring of 3 k-slices of 32: (16KB A + 8KB B) x 3 = 72 KB
// -> TWO blocks resident per CU (144 KB LDS, ~240 regs with bounds(256,2)).
// Rationale: chunk wall-time was 2567 cyc vs 1242 cyc MFMA with no pipe >55%
// busy -> lockstep latency serialization; a second independent barrier domain
// per CU fills the gaps (m114 mechanism). Per-CU MFMA/LDS intensity unchanged.
// Pipeline: stage chunk c+2 during c (overwrites slice (c-1)%3, sealed by the
// chunk-c entry barrier -> race-free). 6 loads/chunk/thread; counted WAITV(6)
// at entry (c landed, c+1 in flight) -- never drains to 0 until the tail.
// LDS swizzle: 16B slot S(row,s) = (row>>1)*8 + (((row&1)*4+s)^((row>>1)&7));
// applied on ds_read addr, inverted on per-thread GLOBAL source (LDS dest of
// global_load_lds stays lane-linear). Worst case 2-way on ds_read_b128 (free).
// XCD swizzle: 1536 blocks = 8 XCD x 3 rounds x 64 slots (4y x 16x rectangle):
// per-XCD concurrent A working set = 4 tiles x 256 rows = 2 MB -> fits 4 MB L2.

#define WAITV(N) asm volatile("s_waitcnt vmcnt(" #N ")" ::: "memory")
#define LGKM0 asm volatile("s_waitcnt lgkmcnt(0)" ::: "memory"); \
              __builtin_amdgcn_sched_barrier(0)

#define MM2(I, AL, AH)                                                        \
    __builtin_amdgcn_s_setprio(1);                                            \
    _Pragma("unroll") for (int nt = 0; nt < 4; ++nt)                          \
        acc[(I)][nt] = __builtin_amdgcn_mfma_f32_16x16x32_bf16(               \
            (AL), bF[nt], acc[(I)][nt], 0, 0, 0);                             \
    _Pragma("unroll") for (int nt = 0; nt < 4; ++nt)                          \
        acc[(I) + 1][nt] = __builtin_amdgcn_mfma_f32_16x16x32_bf16(           \
            (AH), bF[nt], acc[(I) + 1][nt], 0, 0, 0);                         \
    __builtin_amdgcn_s_setprio(0);                                            \
    __builtin_amdgcn_sched_barrier(0);

#define CHUNK(cexpr, SL, DOSTAGE)                                             \
  {                                                                           \
    __builtin_amdgcn_s_barrier();                                             \
    __builtin_amdgcn_sched_barrier(0);                                        \
    const int c_ = (cexpr);                                                   \
    const char* aB_ = AsB + (SL) * 16384;                                     \
    const char* bB_ = BsB + (SL) * 8192;                                      \
    bf16x8 bF[4], aL0, aH0, aL1, aH1;                                         \
    _Pragma("unroll") for (int nt = 0; nt < 4; ++nt)                          \
        bF[nt] = *(const bf16x8*)(bB_ + SB0 + nt * 1024);                     \
    aL0 = *(const bf16x8*)(aB_ + SA0);                                        \
    aH0 = *(const bf16x8*)(aB_ + SA0 + 1024);                                 \
    LGKM0;                                                                    \
    aL1 = *(const bf16x8*)(aB_ + SA0 + 2048);                                 \
    aH1 = *(const bf16x8*)(aB_ + SA0 + 3072);                                 \
    if (DOSTAGE) {                                                            \
      unsigned short* ad_ =                                                   \
          (unsigned short*)(AsL + (((SL) + 2) % 3) * 16384);                  \
      const int ko_ = (c_ + 2) * BKC;                                         \
      async16(aGp0 + ko_, ad_ + (tid + 0) * 8);                               \
      async16(aGp1 + ko_, ad_ + (tid + 256) * 8);                             \
      async16(aGp2 + ko_, ad_ + (tid + 512) * 8);                             \
      async16(aGp3 + ko_, ad_ + (tid + 768) * 8);                             \
    }                                                                         \
    MM2(0, aL0, aH0);                                                         \
    LGKM0;                                                                    \
    aL0 = *(const bf16x8*)(aB_ + SA0 + 4096);                                 \
    aH0 = *(const bf16x8*)(aB_ + SA0 + 5120);                                 \
    if (DOSTAGE) {                                                            \
      unsigned short* bd_ =                                                   \
          (unsigned short*)(BsL + (((SL) + 2) % 3) * 8192);                   \
      const int ko_ = (c_ + 2) * BKC;                                         \
      async16(bGp0 + ko_, bd_ + (tid + 0) * 8);                               \
      async16(bGp1 + ko_, bd_ + (tid + 256) * 8);                             \
    }                                                                         \
    MM2(2, aL1, aH1);                                                         \
    LGKM0;                                                                    \
    aL1 = *(const bf16x8*)(aB_ + SA0 + 6144);                                 \
    aH1 = *(const bf16x8*)(aB_ + SA0 + 7168);                                 \
    MM2(4, aL0, aH0);                                                         \
    LGKM0;                                                                    \
    MM2(6, aL1, aH1);                                                         \
  }

__global__ __launch_bounds__(256, 2) void gemm_kernel(const unsigned short* __restrict__ A,
                                                      const unsigned short* __restrict__ Bt,
                                                      unsigned short* __restrict__ U) {
  __shared__ alignas(16) unsigned short As[3][BM * BKC];  // 48 KB
  __shared__ alignas(16) unsigned short Bs[3][BN * BKC];  // 24 KB
  const int tid  = threadIdx.x;
  const int wave = tid >> 6, lane = tid & 63;
  const int quad = lane >> 4, lrow = lane & 15;
  const int wm = (wave >> 1) * 128;  // 2 M-waves
  const int wn = (wave & 1) * 64;    // 2 N-waves

  // XCD swizzle: 1536 = 8 XCD x 3 rounds x 64 slots; rectangle 4y x 16x.
  const int f    = blockIdx.y * gridDim.x + blockIdx.x;
  const int xcd  = f & 7;
  const int slot = f >> 3;           // 0..191
  const int rnd  = slot >> 6;        // 0..2
  const int ss   = slot & 63;        // 0..63
  const int mBase = (4 * xcd + (ss & 3)) * BM;    // y-tile 0..31
  const int nBase = (16 * rnd + (ss >> 2)) * BN;  // x-tile 0..47

  floatx4 acc[8][4] = {};

  // staging: thread owns 16B slots L = tid + j*256 of each slice (lane-linear
  // LDS dest). Invert swizzle to find the (row, k-slot) each slot must hold.
  int rr[4], sv[4];
#pragma unroll
  for (int j = 0; j < 4; ++j) {
    const int Lj = tid + j * 256;
    const int p = Lj >> 3, w = Lj & 7, v = w ^ (p & 7);
    rr[j] = 2 * p + (v >> 2); sv[j] = v & 3;
  }
  const unsigned short* aGp0 = A + (size_t)(mBase + rr[0]) * GK + sv[0] * 8;
  const unsigned short* aGp1 = A + (size_t)(mBase + rr[1]) * GK + sv[1] * 8;
  const unsigned short* aGp2 = A + (size_t)(mBase + rr[2]) * GK + sv[2] * 8;
  const unsigned short* aGp3 = A + (size_t)(mBase + rr[3]) * GK + sv[3] * 8;
  const unsigned short* bGp0 = Bt + (size_t)(nBase + rr[0]) * GK + sv[0] * 8;
  const unsigned short* bGp1 = Bt + (size_t)(nBase + rr[1]) * GK + sv[1] * 8;

  // ds_read byte offsets within a slice (+16 rows = +1024 B; XOR term invariant)
  const int rA = wm + lrow;
  const int SA0 = (rA >> 1) * 128 + ((((rA & 1) * 4 + quad) ^ ((rA >> 1) & 7)) * 16);
  const int rB = wn + lrow;
  const int SB0 = (rB >> 1) * 128 + ((((rB & 1) * 4 + quad) ^ ((rB >> 1) & 7)) * 16);
  const char* AsB = (const char*)As;
  const char* BsB = (const char*)Bs;
  char* AsL = (char*)As;
  char* BsL = (char*)Bs;

  // prologue: stage chunks 0,1 (12 loads/thread in flight)
#pragma unroll
  for (int c = 0; c < 2; ++c) {
    unsigned short* ad = (unsigned short*)(AsL + c * 16384);
    unsigned short* bd = (unsigned short*)(BsL + c * 8192);
    async16(aGp0 + c * BKC, ad + (tid + 0) * 8);
    async16(aGp1 + c * BKC, ad + (tid + 256) * 8);
    async16(aGp2 + c * BKC, ad + (tid + 512) * 8);
    async16(aGp3 + c * BKC, ad + (tid + 768) * 8);
    async16(bGp0 + c * BKC, bd + (tid + 0) * 8);
    async16(bGp1 + c * BKC, bd + (tid + 256) * 8);
  }

  // main loop: chunks 0..59 (stage c+2), then peeled 60..63
#pragma unroll 1
  for (int cc = 0; cc < 20; ++cc) {
    const int cb = cc * 3;
    WAITV(6); CHUNK(cb + 0, 0, true);
    WAITV(6); CHUNK(cb + 1, 1, true);
    WAITV(6); CHUNK(cb + 2, 2, true);
  }
  WAITV(6); CHUNK(60, 0, true);   // stages 62
  WAITV(6); CHUNK(61, 1, true);   // stages 63
  WAITV(6); CHUNK(62, 2, false);
  WAITV(0); CHUNK(63, 0, false);

  // C/D layout: col = lane&15 (N), row = quad*4 + reg (M). Flat U: col = gn.
#pragma unroll
  for (int mt = 0; mt < 8; ++mt) {
    const int gm = mBase + wm + mt * 16 + quad * 4;
#pragma unroll
    for (int nt = 0; nt < 4; ++nt) {
      const int gn = nBase + wn + nt * 16 + lrow;
#pragma unroll
      for (int q = 0; q < 4; ++q)
        U[(size_t)(gm + q) * GN + gn] = f2bf(acc[mt][nt][q]);
    }
  }
}

// ---------------- SRU scan (flat layout: u0 plane, u1u2 interleaved, x in A_bf) -
// U row gm: [u0: d=0..2047][u1u2 interleaved: cols 2048+2d, 2048+2d+1].
// Rotating raw-register prefetch depth 16 -> 48 outstanding vm-ops (<=63 cap).
__global__ __launch_bounds__(64) void sru_scan_flat(const unsigned short* __restrict__ U,
                                                    const unsigned short* __restrict__ xbf,
                                                    const float* __restrict__ c0,
                                                    const float* __restrict__ wc,
                                                    const float* __restrict__ bias,
                                                    float* __restrict__ out) {
  const int e = blockIdx.x * 64 + threadIdx.x;
  const int b = e >> 11, d = e & (DIM - 1);
  const float vf = wc[d], vr = wc[DIM + d];
  const float bfv = bias[d], brv = bias[DIM + d];
  float c = c0[e];

  constexpr int PF = SCAN_PF;
  constexpr int US = BATCH * GN;
  constexpr int XS = BATCH * DIM;

  const unsigned short* u0p  = U + (size_t)b * GN + d;
  const unsigned short* u12p = U + (size_t)b * GN + DIM + 2 * d;
  const unsigned short* xp   = xbf + (size_t)b * DIM + d;
  float* hp = out + (size_t)b * DIM + d;

  unsigned pu0[PF], pu12[PF], pux[PF];
#pragma unroll
  for (int j = 0; j < PF; ++j) {
    pu0[j]  = u0p[(size_t)j * US];
    pu12[j] = *(const unsigned*)(u12p + (size_t)j * US);
    pux[j]  = xp[(size_t)j * XS];
  }
  const unsigned short* uf0  = u0p + (size_t)PF * US;
  const unsigned short* uf12 = u12p + (size_t)PF * US;
  const unsigned short* xf   = xp + (size_t)PF * XS;

  for (int l0 = 0; l0 < L_SEQ; l0 += PF) {
#pragma unroll
    for (int j = 0; j < PF; ++j) {
      const unsigned r0 = pu0[j], r12 = pu12[j], rx = pux[j];
      pu0[j]  = uf0[0];
      pu12[j] = *(const unsigned*)uf12;
      pux[j]  = xf[0];
      uf0 += US; uf12 += US; xf += XS;
      const float a0 = __uint_as_float(r0 << 16);
      const float u1 = __uint_as_float(r12 << 16);
      const float u2 = __uint_as_float(r12 & 0xFFFF0000u);
      const float ax = __uint_as_float(rx << 16) * SCALE_X;
      const float f = sigmoidf_fast(u1 + fmaf(vf, c, bfv));
      c = fmaf(c - a0, f, a0);
      const float rr = sigmoidf_fast(u2 + fmaf(vr, c, brv));
      *hp = fmaf(rr, c - ax, ax);
      hp += XS;
    }
  }
  out[(size_t)L_SEQ * XS + e] = c;
}

// --------------------------------- launcher ------------------------------------
extern "C" void kernel_launch(void* const* d_in, const int* in_sizes, int n_in,
                              void* d_out, int out_size, void* d_ws, size_t ws_size,
                              hipStream_t stream) {
  const float* x    = (const float*)d_in[0];
  const float* c0   = (const float*)d_in[1];
  const float* W    = (const float*)d_in[2];
  const float* wc   = (const float*)d_in[3];
  const float* bias = (const float*)d_in[4];
  float* out = (float*)d_out;

  char* ws = (char*)d_ws;
  // flat layout: A 33,554,432 (+512K scan-overread pad) | Bt 25,165,824 |
  //              U 100,663,296 (+2M scan-overread pad)
  unsigned short* A_bf  = (unsigned short*)(ws);
  unsigned short* Bt_bf = (unsigned short*)(ws + 34078720);
  unsigned short* U_bf  = (unsigned short*)(ws + 59244544);

  cast_x_kernel<<<4096, 256, 0, stream>>>((const float4*)x, A_bf);
  transpose_w_kernel<<<dim3(GN / 32, GK / 32), 256, 0, stream>>>(W, Bt_bf);
  gemm_kernel<<<dim3(GN / BN, GM / BM), 256, 0, stream>>>(A_bf, Bt_bf, U_bf);
  sru_scan_flat<<<256, 64, 0, stream>>>(U_bf, A_bf, c0, wc, bias, out);
}

// Round 5
// 438.029 us; speedup vs baseline: 1.0429x; 1.0308x over previous
//
#include <hip/hip_runtime.h>
#include <stdint.h>

// Problem constants (fixed by reference: L=1024, B=8, D=2048)
#define L_SEQ 1024
#define BATCH 8
#define DIM   2048
#define GM    8192   // L*B
#define GN    6144   // 3*D
#define GK    2048   // D
#define SCALE_X 1.7320508075688772f  // sqrt(1 + 2*exp(0))
#define SCAN_PF 16

// GEMM geometry: 256x256 tile, 8 waves (2M x 4N), k-ring of 4 slices of 32
#define BM 256
#define BN 256
#define BKC 32

using bf16x8  = __attribute__((ext_vector_type(8))) __bf16;
using floatx4 = __attribute__((ext_vector_type(4))) float;

__device__ __forceinline__ unsigned short f2bf(float f) {
  unsigned u = __float_as_uint(f);
  u += 0x7FFFu + ((u >> 16) & 1u);   // round-to-nearest-even
  return (unsigned short)(u >> 16);
}
__device__ __forceinline__ float sigmoidf_fast(float z) {
  return __builtin_amdgcn_rcpf(1.0f + __expf(-z));
}
__device__ __forceinline__ void async16(const unsigned short* g, unsigned short* l) {
  __builtin_amdgcn_global_load_lds(
      (__attribute__((address_space(1))) unsigned int*)g,
      (__attribute__((address_space(3))) unsigned int*)l,
      16, 0, 0);
}

// ------------- fused prep: cast x -> A (bf16)  +  transpose-cast W -> Bt --------
// Blocks [0, 12288): transpose tiles (n-tile = blk%192, k-tile = blk/192).
// Blocks [12288, 16384): grid-stride streaming cast of x.
// W col n = 3d+j -> j==0: Bt row d (u0 plane); j>0: Bt row DIM + 2d + (j-1).
__global__ __launch_bounds__(256) void prep_kernel(const float4* __restrict__ xin,
                                                   unsigned short* __restrict__ Aout,
                                                   const float* __restrict__ W,
                                                   unsigned short* __restrict__ Bt) {
  __shared__ float tile[32][33];
  const int blk = blockIdx.x;
  if (blk < 12288) {
    const int tx = threadIdx.x & 31, ty = threadIdx.x >> 5;
    const int n0 = (blk % 192) * 32;
    const int k0 = (blk / 192) * 32;
#pragma unroll
    for (int r = 0; r < 32; r += 8)
      tile[ty + r][tx] = W[(size_t)(k0 + ty + r) * GN + n0 + tx];
    __syncthreads();
#pragma unroll
    for (int r = 0; r < 32; r += 8) {
      const int n = n0 + ty + r;
      const int dq = n / 3, j = n - 3 * dq;
      const int np = (j == 0) ? dq : (DIM + 2 * dq + (j - 1));
      Bt[(size_t)np * GK + k0 + tx] = f2bf(tile[tx][ty + r]);
    }
  } else {
    const int n4 = (GM * GK) / 4;
    for (int i = (blk - 12288) * 256 + threadIdx.x; i < n4; i += 4096 * 256) {
      float4 v = xin[i];
      union { unsigned short s[4]; unsigned long long ll; } o;
      o.s[0] = f2bf(v.x); o.s[1] = f2bf(v.y); o.s[2] = f2bf(v.z); o.s[3] = f2bf(v.w);
      *(unsigned long long*)&Aout[(size_t)i * 4] = o.ll;
    }
  }
}

// ---------------- GEMM: U = A(GM x GK) * Bt(GN x GK)^T, bf16 out ----------------
// 256x256 tile, 8 waves (2M x 4N), per-wave 128x64 = 8x4 reps of 16x16x32 MFMA.
// LDS = ring of 4 k-slices (k=32 each) per matrix: 4*16KB*2 = 128 KB, 1 blk/CU.
//
// Strict phase alternation (this round's change, m201's double-barrier form):
// per chunk c:  WAITV(8) ; BAR0 ; R0-burst(bF0-3,aF0-3 = 8 ds_read_b128) +
// stageA(c+3) ; BAR1 ; lgkm0 ; 16 MFMA (acc0-3) ; BAR2 ; R1-burst(aF4-7) +
// stageB(c+3) ; BAR3 ; lgkm0 ; 16 MFMA (acc4-7) ; [next chunk's BAR0].
// Rationale: measured chunk = 2637 cyc ~ MFMA(1242) + LDS(~1300) ADDED -- mixed
// read/MFMA issue never overlaps the pipes in any of 4 prior variants. Strict
// alternation runs each pipe at its max burst rate within its window (m201: 62%
// MfmaUtil at identical read:MFMA ratio and 2 waves/SIMD).
// Race-safety: per-wave vmcnt -> slice-c reads sit AFTER BAR0 (all waves passed
// their own WAITV(8)); stage of slice (c-1)&3 sits after BAR0, which follows
// every wave's lgkm0-sealed final read of that slice (chunk c-1, R1).
// vmcnt never drains to 0 in the main loop; tail peels 61/62/63 with 8/4/0.
//
// LDS swizzle: 16B slot S(row,s) = (row>>1)*8 + (((row&1)*4+s)^((row>>1)&7));
// applied on ds_read addr, inverted on per-thread GLOBAL source (LDS dest of
// global_load_lds stays lane-linear). Worst case 2-way on ds_read_b128 (free).
// XCD-rectangle swizzle: f -> xcd=f&7, rnd, ss -> 4y x 8x rectangles per XCD
// (A working set 4 MB fits per-XCD L2; FETCH 176->148 MB measured).

#define WAITV(N) asm volatile("s_waitcnt vmcnt(" #N ")" ::: "memory")
#define LGKM0 asm volatile("s_waitcnt lgkmcnt(0)" ::: "memory"); \
              __builtin_amdgcn_sched_barrier(0)

#define CHUNK(cexpr, SL, DOSTAGE)                                             \
  {                                                                           \
    __builtin_amdgcn_s_barrier();  /* BAR0 */                                 \
    __builtin_amdgcn_sched_barrier(0);                                        \
    const int c_ = (cexpr);                                                   \
    const char* aB_ = AsB + (SL) * 16384;                                     \
    const char* bB_ = BsB + (SL) * 16384;                                     \
    bf16x8 bF[4], aF[4];                                                      \
    _Pragma("unroll") for (int nt = 0; nt < 4; ++nt)                          \
        bF[nt] = *(const bf16x8*)(bB_ + SB0 + nt * 1024);                     \
    _Pragma("unroll") for (int mt = 0; mt < 4; ++mt)                          \
        aF[mt] = *(const bf16x8*)(aB_ + SA0 + mt * 1024);                     \
    if (DOSTAGE) {                                                            \
      unsigned short* ad_ = (unsigned short*)(AsL + ((c_ + 3) & 3) * 16384);  \
      const int ko_ = (c_ + 3) * BKC;                                         \
      async16(aG0 + ko_, ad_ + L0 * 8);                                       \
      async16(aG1 + ko_, ad_ + L1 * 8);                                       \
    }                                                                         \
    __builtin_amdgcn_sched_barrier(0);                                        \
    __builtin_amdgcn_s_barrier();  /* BAR1: read-burst | MFMA-burst fence */  \
    LGKM0;                                                                    \
    __builtin_amdgcn_s_setprio(1);                                            \
    _Pragma("unroll") for (int mt = 0; mt < 4; ++mt)                          \
      _Pragma("unroll") for (int nt = 0; nt < 4; ++nt)                        \
        acc[mt][nt] = __builtin_amdgcn_mfma_f32_16x16x32_bf16(                \
            aF[mt], bF[nt], acc[mt][nt], 0, 0, 0);                            \
    __builtin_amdgcn_s_setprio(0);                                            \
    __builtin_amdgcn_sched_barrier(0);                                        \
    __builtin_amdgcn_s_barrier();  /* BAR2 */                                 \
    _Pragma("unroll") for (int mt = 0; mt < 4; ++mt)                          \
        aF[mt] = *(const bf16x8*)(aB_ + SA0 + 4096 + mt * 1024);              \
    if (DOSTAGE) {                                                            \
      unsigned short* bd_ = (unsigned short*)(BsL + ((c_ + 3) & 3) * 16384);  \
      const int ko_ = (c_ + 3) * BKC;                                         \
      async16(bG0 + ko_, bd_ + L0 * 8);                                       \
      async16(bG1 + ko_, bd_ + L1 * 8);                                       \
    }                                                                         \
    __builtin_amdgcn_sched_barrier(0);                                        \
    __builtin_amdgcn_s_barrier();  /* BAR3 */                                 \
    LGKM0;                                                                    \
    __builtin_amdgcn_s_setprio(1);                                            \
    _Pragma("unroll") for (int mt = 0; mt < 4; ++mt)                          \
      _Pragma("unroll") for (int nt = 0; nt < 4; ++nt)                        \
        acc[mt + 4][nt] = __builtin_amdgcn_mfma_f32_16x16x32_bf16(            \
            aF[mt], bF[nt], acc[mt + 4][nt], 0, 0, 0);                        \
    __builtin_amdgcn_s_setprio(0);                                            \
    __builtin_amdgcn_sched_barrier(0);                                        \
  }

__global__ __launch_bounds__(512, 2) void gemm_kernel(const unsigned short* __restrict__ A,
                                                      const unsigned short* __restrict__ Bt,
                                                      unsigned short* __restrict__ U) {
  __shared__ alignas(16) unsigned short As[4][BM * BKC];  // 64 KB
  __shared__ alignas(16) unsigned short Bs[4][BN * BKC];  // 64 KB
  const int tid  = threadIdx.x;
  const int wave = tid >> 6, lane = tid & 63;
  const int quad = lane >> 4, lrow = lane & 15;
  const int wm = (wave >> 2) * 128;  // 2 M-waves
  const int wn = (wave & 3) * 64;    // 4 N-waves

  // XCD-rectangle swizzle: 768 blocks = 8 XCD x 3 rounds x 32 slots (4y x 8x)
  const int f    = blockIdx.y * (GN / BN) + blockIdx.x;
  const int xcd  = f & 7;
  const int slot = f >> 3;
  const int rnd  = slot >> 5;        // 0..2
  const int ss   = slot & 31;        // 0..31
  const int mBase = (4 * xcd + (ss & 3)) * BM;   // y-tile 0..31
  const int nBase = (8 * rnd + (ss >> 2)) * BN;  // x-tile 0..23

  floatx4 acc[8][4] = {};

  // staging: thread owns 16B slots L0=tid, L1=tid+512 of each slice (lane-linear
  // LDS dest). Invert swizzle to find the (row, k-slot) this slot must hold.
  const int L0 = tid, L1 = tid + 512;
  int r0, s0, r1, s1;
  { const int p = L0 >> 3, w = L0 & 7, v = w ^ (p & 7); r0 = 2 * p + (v >> 2); s0 = v & 3; }
  { const int p = L1 >> 3, w = L1 & 7, v = w ^ (p & 7); r1 = 2 * p + (v >> 2); s1 = v & 3; }
  const unsigned short* aG0 = A  + (size_t)(mBase + r0) * GK + s0 * 8;
  const unsigned short* aG1 = A  + (size_t)(mBase + r1) * GK + s1 * 8;
  const unsigned short* bG0 = Bt + (size_t)(nBase + r0) * GK + s0 * 8;
  const unsigned short* bG1 = Bt + (size_t)(nBase + r1) * GK + s1 * 8;

  // ds_read byte offsets within a slice (+16 rows = +1024 B)
  const int rA = wm + lrow;
  const int SA0 = (rA >> 1) * 128 + ((((rA & 1) * 4 + quad) ^ ((rA >> 1) & 7)) * 16);
  const int rB = wn + lrow;
  const int SB0 = (rB >> 1) * 128 + ((((rB & 1) * 4 + quad) ^ ((rB >> 1) & 7)) * 16);
  const char* AsB = (const char*)As;
  const char* BsB = (const char*)Bs;
  char* AsL = (char*)As;
  char* BsL = (char*)Bs;

  // prologue: stage chunks 0,1,2 (12 loads/thread in flight)
#pragma unroll
  for (int c = 0; c < 3; ++c) {
    unsigned short* ad = (unsigned short*)(AsL + c * 16384);
    unsigned short* bd = (unsigned short*)(BsL + c * 16384);
    async16(aG0 + c * BKC, ad + L0 * 8);
    async16(aG1 + c * BKC, ad + L1 * 8);
    async16(bG0 + c * BKC, bd + L0 * 8);
    async16(bG1 + c * BKC, bd + L1 * 8);
  }

  // main loop: chunks 0..59 (stage c+3), then peeled 60..63
#pragma unroll 1
  for (int cc = 0; cc < 15; ++cc) {
    const int cb = cc * 4;
#pragma unroll
    for (int j = 0; j < 4; ++j) {
      WAITV(8);
      CHUNK(cb + j, j, true);
    }
  }
  WAITV(8); CHUNK(60, 0, true);   // stages chunk 63
  WAITV(8); CHUNK(61, 1, false);
  WAITV(4); CHUNK(62, 2, false);
  WAITV(0); CHUNK(63, 3, false);

  // C/D layout: col = lane&15 (N), row = quad*4 + reg (M). Flat U: col = gn.
#pragma unroll
  for (int mt = 0; mt < 8; ++mt) {
    const int gm = mBase + wm + mt * 16 + quad * 4;
#pragma unroll
    for (int nt = 0; nt < 4; ++nt) {
      const int gn = nBase + wn + nt * 16 + lrow;
#pragma unroll
      for (int q = 0; q < 4; ++q)
        U[(size_t)(gm + q) * GN + gn] = f2bf(acc[mt][nt][q]);
    }
  }
}

// ---------------- SRU scan (flat layout: u0 plane, u1u2 interleaved, x in A_bf) -
// U row gm: [u0: d=0..2047][u1u2 interleaved: cols 2048+2d, 2048+2d+1].
// Rotating raw-register prefetch depth 16 -> 48 outstanding vm-ops (<=63 cap).
__global__ __launch_bounds__(64) void sru_scan_flat(const unsigned short* __restrict__ U,
                                                    const unsigned short* __restrict__ xbf,
                                                    const float* __restrict__ c0,
                                                    const float* __restrict__ wc,
                                                    const float* __restrict__ bias,
                                                    float* __restrict__ out) {
  const int e = blockIdx.x * 64 + threadIdx.x;
  const int b = e >> 11, d = e & (DIM - 1);
  const float vf = wc[d], vr = wc[DIM + d];
  const float bfv = bias[d], brv = bias[DIM + d];
  float c = c0[e];

  constexpr int PF = SCAN_PF;
  constexpr int US = BATCH * GN;
  constexpr int XS = BATCH * DIM;

  const unsigned short* u0p  = U + (size_t)b * GN + d;
  const unsigned short* u12p = U + (size_t)b * GN + DIM + 2 * d;
  const unsigned short* xp   = xbf + (size_t)b * DIM + d;
  float* hp = out + (size_t)b * DIM + d;

  unsigned pu0[PF], pu12[PF], pux[PF];
#pragma unroll
  for (int j = 0; j < PF; ++j) {
    pu0[j]  = u0p[(size_t)j * US];
    pu12[j] = *(const unsigned*)(u12p + (size_t)j * US);
    pux[j]  = xp[(size_t)j * XS];
  }
  const unsigned short* uf0  = u0p + (size_t)PF * US;
  const unsigned short* uf12 = u12p + (size_t)PF * US;
  const unsigned short* xf   = xp + (size_t)PF * XS;

  for (int l0 = 0; l0 < L_SEQ; l0 += PF) {
#pragma unroll
    for (int j = 0; j < PF; ++j) {
      const unsigned r0 = pu0[j], r12 = pu12[j], rx = pux[j];
      pu0[j]  = uf0[0];
      pu12[j] = *(const unsigned*)uf12;
      pux[j]  = xf[0];
      uf0 += US; uf12 += US; xf += XS;
      const float a0 = __uint_as_float(r0 << 16);
      const float u1 = __uint_as_float(r12 << 16);
      const float u2 = __uint_as_float(r12 & 0xFFFF0000u);
      const float ax = __uint_as_float(rx << 16) * SCALE_X;
      const float f = sigmoidf_fast(u1 + fmaf(vf, c, bfv));
      c = fmaf(c - a0, f, a0);
      const float rr = sigmoidf_fast(u2 + fmaf(vr, c, brv));
      *hp = fmaf(rr, c - ax, ax);
      hp += XS;
    }
  }
  out[(size_t)L_SEQ * XS + e] = c;
}

// --------------------------------- launcher ------------------------------------
extern "C" void kernel_launch(void* const* d_in, const int* in_sizes, int n_in,
                              void* d_out, int out_size, void* d_ws, size_t ws_size,
                              hipStream_t stream) {
  const float* x    = (const float*)d_in[0];
  const float* c0   = (const float*)d_in[1];
  const float* W    = (const float*)d_in[2];
  const float* wc   = (const float*)d_in[3];
  const float* bias = (const float*)d_in[4];
  float* out = (float*)d_out;

  char* ws = (char*)d_ws;
  // flat layout: A 33,554,432 (+512K scan-overread pad) | Bt 25,165,824 |
  //              U 100,663,296 (+2M scan-overread pad)
  unsigned short* A_bf  = (unsigned short*)(ws);
  unsigned short* Bt_bf = (unsigned short*)(ws + 34078720);
  unsigned short* U_bf  = (unsigned short*)(ws + 59244544);

  prep_kernel<<<16384, 256, 0, stream>>>((const float4*)x, A_bf, W, Bt_bf);
  gemm_kernel<<<dim3(GN / BN, GM / BM), 512, 0, stream>>>(A_bf, Bt_bf, U_bf);
  sru_scan_flat<<<256, 64, 0, stream>>>(U_bf, A_bf, c0, wc, bias, out);
}